// Round 13
// baseline (87.728 us; speedup 1.0000x reference)
//
#include <hip/hip_runtime.h>
#include <stdint.h>

#define N_ANCH 147456
#define NGT 128

// d_ws layout: lab (N_ANCH B) | keys (N_ANCH u32) | ctl (u32 words below).
// NOTHING needs zero-init: every word read is unconditionally written earlier
// in the same call by a prior kernel (plain disjoint stores, no atomics).
#define W_CNTS   0      // 576 x {cntPos, cntNeg}
#define W_GMAX2  1160   // 1024 u64 slots (byte off 4640: 8B-aligned)

typedef unsigned long long u64;

__constant__ float c_base[9][4] = {
  {-84.f,-40.f,99.f,55.f},     // r=0.5 s=8
  {-176.f,-88.f,191.f,103.f},  // r=0.5 s=16
  {-360.f,-184.f,375.f,199.f}, // r=0.5 s=32
  {-56.f,-56.f,71.f,71.f},     // r=1   s=8
  {-120.f,-120.f,135.f,135.f}, // r=1   s=16
  {-248.f,-248.f,263.f,263.f}, // r=1   s=32
  {-36.f,-80.f,51.f,95.f},     // r=2   s=8
  {-80.f,-168.f,95.f,183.f},   // r=2   s=16
  {-168.f,-344.f,183.f,359.f}, // r=2   s=32
};
// exact per-type anchor areas (W*H, integers < 2^24 -> bitwise == __fmul_rn result)
__constant__ float c_areaA[9] = {
  17664.f, 70656.f, 282624.f,
  16384.f, 65536.f, 262144.f,
  15488.f, 61952.f, 247808.f,
};
// extents over all 9 types: x1min=-360 x2max=375 y1min=-344 y2max=359

__host__ __device__ inline uint32_t rotl32(uint32_t v, int d){ return (v<<d)|(v>>(32-d)); }

// JAX Threefry-2x32, 20 rounds
__host__ __device__ inline void tf2x32(uint32_t k0, uint32_t k1, uint32_t x0, uint32_t x1,
                                       uint32_t* o0, uint32_t* o1){
  uint32_t ks0=k0, ks1=k1, ks2=k0^k1^0x1BD11BDAu;
  x0 += ks0; x1 += ks1;
  #define TFR(r) { x0 += x1; x1 = rotl32(x1,(r)); x1 ^= x0; }
  TFR(13) TFR(15) TFR(26) TFR(6)   x0+=ks1; x1+=ks2+1u;
  TFR(17) TFR(29) TFR(16) TFR(24)  x0+=ks2; x1+=ks0+2u;
  TFR(13) TFR(15) TFR(26) TFR(6)   x0+=ks0; x1+=ks1+3u;
  TFR(17) TFR(29) TFR(16) TFR(24)  x0+=ks1; x1+=ks2+4u;
  TFR(13) TFR(15) TFR(26) TFR(6)   x0+=ks2; x1+=ks0+5u;
  #undef TFR
  *o0=x0; *o1=x1;
}

// jax_threefry_partitionable=True: bits(j) = o0^o1 of enc(0,j); key = top 23 bits
__device__ inline uint32_t rand_m23(uint32_t k0, uint32_t k1, uint32_t j){
  uint32_t a, b;
  tf2x32(k0, k1, 0u, j, &a, &b);
  return (a ^ b) >> 9;
}

// kA: blocks <576: per-anchor labels/keys/targets + per-block counts,
//     scanning only the block-relevant gt list (ballot-compacted, index order).
//     blocks >=576: per-(gt,slice) argmax over the gt's overlap window only.
// IoU bitwise-identical to reference path (areas hoisted, same rounding,
// quick-reject ov=+0 == 0/denom).
__global__ __launch_bounds__(256) void kA(const float* __restrict__ gt,
                                          const float* __restrict__ meta,
                                          signed char* __restrict__ lab,
                                          uint32_t* __restrict__ keys,
                                          uint32_t* __restrict__ ctl,
                                          float* __restrict__ out,
                                          uint32_t pk0,uint32_t pk1,
                                          uint32_t nk0,uint32_t nk1){
  int bid = blockIdx.x;
  float W = meta[1], H = meta[0];
  if (bid < 576){
    __shared__ float4 sg[NGT];
    __shared__ float  sB[NGT];
    __shared__ uint32_t slist[NGT];
    __shared__ unsigned long long sball[2];
    __shared__ uint32_t c0, c1;
    if (threadIdx.x == 0){ c0 = 0u; c1 = 0u; }
    for (int t = threadIdx.x; t < NGT; t += 256){
      float4 G = reinterpret_cast<const float4*>(gt)[t];
      sg[t] = G;
      sB[t] = __fmul_rn(G.z - G.x + 1.0f, G.w - G.y + 1.0f);
    }
    // block anchor region (all 9 types' extents + 1px float slop)
    int i0 = bid*256, k0 = i0/9, k1 = (i0+255)/9;
    int y0 = k0 >> 7, y1 = k1 >> 7;
    int x0 = (y0==y1) ? (k0 & 127) : 0, x1 = (y0==y1) ? (k1 & 127) : 127;
    float Rxlo = 16.f*x0 - 361.f, Rxhi = 16.f*x1 + 376.f;
    float Rylo = 16.f*y0 - 345.f, Ryhi = 16.f*y1 + 360.f;
    __syncthreads();
    if (threadIdx.x < NGT){
      float4 G = sg[threadIdx.x];
      bool rel = (G.x <= Rxhi) && (G.z >= Rxlo) && (G.y <= Ryhi) && (G.w >= Rylo);
      unsigned long long b = __ballot(rel);
      if ((threadIdx.x & 63) == 0) sball[threadIdx.x >> 6] = b;
    }
    __syncthreads();
    unsigned long long b0 = sball[0], b1 = sball[1];
    if (threadIdx.x < NGT){
      float4 G = sg[threadIdx.x];
      bool rel = (G.x <= Rxhi) && (G.z >= Rxlo) && (G.y <= Ryhi) && (G.w >= Rylo);
      if (rel){
        int lane = threadIdx.x & 63;
        unsigned long long my = (threadIdx.x < 64) ? b0 : b1;
        uint32_t pos = (uint32_t)__popcll(my & ((1ull << lane) - 1ull));
        if (threadIdx.x >= 64) pos += (uint32_t)__popcll(b0);
        slist[pos] = (uint32_t)threadIdx.x;
      }
    }
    __syncthreads();
    int nl = (int)(__popcll(b0) + __popcll(b1));
    int fs;   // first gt index NOT in list (=128 if all in list)
    {
      unsigned long long n0 = ~b0;
      if (n0) fs = __ffsll((long long)n0) - 1;
      else { unsigned long long n1 = ~b1; fs = n1 ? 64 + __ffsll((long long)n1) - 1 : 128; }
    }
    int i = bid*256 + threadIdx.x;
    int k = i / 9; int t9 = i - k*9;
    float sx = 16.0f * (float)(k & 127);
    float sy = 16.0f * (float)(k >> 7);
    float ax1 = c_base[t9][0] + sx, ay1 = c_base[t9][1] + sy;
    float ax2 = c_base[t9][2] + sx, ay2 = c_base[t9][3] + sy;
    float areaA = c_areaA[t9];
    bool inside = (ax1 >= 0.0f) && (ay1 >= 0.0f) && (ax2 < W) && (ay2 < H);
    float best = -1.0f; int arg = 0;   // outside: overlaps all -1 -> argmax 0
    if (inside){
      best = -2.0f;
      for (int li = 0; li < nl; ++li){
        int g = (int)slist[li];
        float4 G = sg[g];
        float iw = fminf(ax2,G.z) - fmaxf(ax1,G.x) + 1.0f;
        float ih = fminf(ay2,G.w) - fmaxf(ay1,G.y) + 1.0f;
        float ov = 0.0f;
        if (iw > 0.0f && ih > 0.0f){
          float inter = __fmul_rn(iw, ih);
          ov = inter / ((areaA + sB[g]) - inter);
        }
        if (ov > best){ best = ov; arg = g; }   // list ascending -> first-occurrence
      }
      if (best < 0.0f){ best = 0.0f; arg = fs; }          // empty list: all-zero row
      else if (best == 0.0f){ arg = (arg < fs) ? arg : fs; } // all-zero row -> idx 0
    }
    signed char L = -1;
    if (best >= 0.7f) L = 1;
    else if (inside && best < 0.3f) L = 0;
    lab[i] = L;
    if (L == 1) keys[i] = rand_m23(pk0,pk1,(uint32_t)i);
    else if (L == 0) keys[i] = rand_m23(nk0,nk1,(uint32_t)i);
    unsigned long long q1 = __ballot(L == 1);
    unsigned long long q0 = __ballot(L == 0);
    if ((threadIdx.x & 63) == 0){
      if (q1) atomicAdd(&c0, (uint32_t)__popcll(q1));
      if (q0) atomicAdd(&c1, (uint32_t)__popcll(q0));
    }
    float4 t4 = make_float4(0.f, 0.f, 0.f, 0.f);
    if (inside){
      float4 G = sg[arg];
      float ew = ax2-ax1+1.0f, eh = ay2-ay1+1.0f;
      float ecx = ax1 + 0.5f*ew, ecy = ay1 + 0.5f*eh;
      float gw = G.z-G.x+1.0f, gh = G.w-G.y+1.0f;
      float gcx = G.x + 0.5f*gw, gcy = G.y + 0.5f*gh;
      t4.x = (gcx-ecx)/ew; t4.y = (gcy-ecy)/eh;
      t4.z = logf(gw/ew);  t4.w = logf(gh/eh);
    }
    *reinterpret_cast<float4*>(out + N_ANCH + 4*(size_t)i) = t4;
    __syncthreads();
    if (threadIdx.x == 0){
      ctl[W_CNTS + 2*bid]     = c0;
      ctl[W_CNTS + 2*bid + 1] = c1;
    }
  } else {
    int b2 = bid - 576;
    int g = b2 >> 3, slice = b2 & 7;
    float bx1=gt[4*g], by1=gt[4*g+1], bx2=gt[4*g+2], by2=gt[4*g+3];
    float areaB = __fmul_rn(bx2-bx1+1.0f, by2-by1+1.0f);
    // overlap-possible position window (+1px float slop)
    int pxl = max(0,   (int)ceilf ((bx1 - 377.0f) * 0.0625f));
    int pxh = min(127, (int)floorf((bx2 + 362.0f) * 0.0625f));
    int pyl = max(0,   (int)ceilf ((by1 - 361.0f) * 0.0625f));
    int pyh = min(127, (int)floorf((by2 + 346.0f) * 0.0625f));
    uint32_t Wp = (uint32_t)(pxh - pxl + 1);
    int tot = (int)Wp * (pyh - pyl + 1);
    // magic division: m = ceil(2^22/Wp); exact for Wp<=128, pos<=16383
    uint32_t mdiv = (4194304u + Wp - 1u) / Wp;
    float a0[9],a1[9],a2[9],a3[9];
    #pragma unroll
    for (int t=0;t<9;++t){ a0[t]=c_base[t][0]; a1[t]=c_base[t][1];
                           a2[t]=c_base[t][2]; a3[t]=c_base[t][3]; }
    float best = -2.0f; int bi = 0;
    for (int pos = slice*256 + threadIdx.x; pos < tot; pos += 2048){
      uint32_t dq = (uint32_t)(((unsigned long long)(uint32_t)pos * mdiv) >> 22);
      int py = pyl + (int)dq;
      int px = pxl + (int)((uint32_t)pos - dq * Wp);
      int k = (py << 7) + px;           // ascending in pos -> first-occurrence ties
      float sx = 16.0f * (float)px;
      float sy = 16.0f * (float)py;
      #pragma unroll
      for (int t = 0; t < 9; ++t){
        float ax1=a0[t]+sx, ay1=a1[t]+sy, ax2=a2[t]+sx, ay2=a3[t]+sy;
        bool inside = (ax1 >= 0.0f) && (ay1 >= 0.0f) && (ax2 < W) && (ay2 < H);
        float iw = fminf(ax2,bx2) - fmaxf(ax1,bx1) + 1.0f;
        float ih = fminf(ay2,by2) - fmaxf(ay1,by1) + 1.0f;
        float ov = inside ? 0.0f : -1.0f;
        if (inside && iw > 0.0f && ih > 0.0f){
          float inter = __fmul_rn(iw, ih);
          ov = inter / ((c_areaA[t] + areaB) - inter);
        }
        if (ov > best){ best = ov; bi = k*9 + t; }
      }
    }
    unsigned long long p = 0ull;
    if (best >= 0.0f)
      p = ((unsigned long long)__float_as_uint(best) << 32) | (uint32_t)(~(uint32_t)bi);
    __shared__ unsigned long long sred[256];
    sred[threadIdx.x] = p;
    __syncthreads();
    for (int s = 128; s > 0; s >>= 1){
      if ((int)threadIdx.x < s){
        unsigned long long q = sred[threadIdx.x + s];
        if (q > sred[threadIdx.x]) sred[threadIdx.x] = q;
      }
      __syncthreads();
    }
    if (threadIdx.x == 0)
      reinterpret_cast<unsigned long long*>(ctl + W_GMAX2)[b2] = sred[0];
  }
}

// kC2 (145 blocks x 1024): every block derives the selection state (winners,
// counts, Tf) from kA's outputs. Blocks 0..143: per-anchor final labels
// (winner override via LDS flag; survivors SKIPPED). Block 144: gathers the
// survivor set by direct lab/keys scan, patches winner overrides, rank-counts,
// writes survivors' labels. Writer disjointness (per anchor, all cases):
//  non-winner: regular writes iff (L<0 | keepAll | key<Tf); special iff key>=Tf.
//  winner rawL==1: wkey==keys[idx] -> identical partition as non-winner pos.
//  winner rawL in {-1,0}: regular uses m=wkey (writes iff keepAll0 or wkey<Tf0);
//   special: ch1 raw entry removed; ch0 entry appended iff !keepAll0 && wkey>=Tf0.
__global__ __launch_bounds__(1024) void kC2(const signed char* __restrict__ lab,
                                            const uint32_t* __restrict__ keys,
                                            float* __restrict__ out,
                                            uint32_t* __restrict__ ctl,
                                            uint32_t pk0, uint32_t pk1){
  int tid = threadIdx.x, bid = blockIdx.x;
  __shared__ uint32_t widx[NGT], wkey[NGT];
  __shared__ signed char wraw[NGT];
  __shared__ unsigned char respf[NGT];
  __shared__ uint32_t wflag[1024];
  __shared__ u64 red[1024];
  __shared__ int sdP, sdN;
  __shared__ uint32_t sel[6];     // 2ch x {Tf, keep, keepAll}
  __shared__ u64 skey[2048];      // [0..1023] ch0, [1024..2047] ch1
  __shared__ uint32_t nctr[2];
  wflag[tid] = 0xFFFFFFFFu;
  if (tid == 0){ sdP = 0; sdN = 0; nctr[0] = 0u; nctr[1] = 0u; }
  u64 acc = 0ull;
  if (tid < 576)
    acc = ((u64)ctl[W_CNTS + 2*tid] << 32) | ctl[W_CNTS + 2*tid + 1];
  red[tid] = acc;
  if (tid < NGT){
    const u64* g2 = reinterpret_cast<const u64*>(ctl + W_GMAX2);
    u64 best = 0ull;
    #pragma unroll
    for (int s = 0; s < 8; ++s){
      u64 q = g2[tid*8 + s];
      if (q > best) best = q;
    }
    uint32_t idx = best ? ~(uint32_t)best : 0xFFFFFFFFu;
    widx[tid] = idx;
    wkey[tid] = (idx != 0xFFFFFFFFu) ? rand_m23(pk0, pk1, idx) : 0u;
  }
  __syncthreads();
  if (tid < NGT){
    uint32_t idx = widx[tid];
    unsigned char rp = 0; signed char rl = -1;
    if (idx != 0xFFFFFFFFu){
      if (bid < 144 && (idx >> 10) == (uint32_t)bid) wflag[idx & 1023u] = wkey[tid];
      bool resp = true;                    // dedup: first gt owns a shared winner
      for (int g = 0; g < tid; ++g) if (widx[g] == idx){ resp = false; break; }
      rl = lab[idx];
      rp = resp ? 1 : 0;
      if (resp && rl != 1){ atomicAdd(&sdP, 1); if (rl == 0) atomicAdd(&sdN, 1); }
    }
    respf[tid] = rp; wraw[tid] = rl;
  }
  __syncthreads();
  for (int off = 512; off > 0; off >>= 1){
    if (tid < off) red[tid] += red[tid + off];
    __syncthreads();
  }
  if (tid == 0){
    uint32_t cntP = (uint32_t)(red[0] >> 32) + (uint32_t)sdP;
    uint32_t cntN = (uint32_t)red[0] - (uint32_t)sdN;
    uint32_t keepP = cntP < 128u ? cntP : 128u;
    uint32_t keepN = cntN < (256u - keepP) ? cntN : (256u - keepP);
    uint32_t cnts[2] = {cntP, cntN}, keeps[2] = {keepP, keepN};
    for (int c = 0; c < 2; ++c){
      uint32_t cnt = cnts[c], keep = keeps[c];
      uint32_t all = (keep >= cnt) ? 1u : 0u, Tf = 0u;
      if (!all){
        u64 slack = 2ull * keep;          // mean survivors ~2*keep (>=8 sigma:
        if (slack < cnt)                  // keep>=128 in any non-keepAll ch)
          Tf = (uint32_t)((((u64)(cnt - slack)) << 23) / cnt);
      }
      sel[c*3+0] = Tf; sel[c*3+1] = keep; sel[c*3+2] = all;
    }
  }
  __syncthreads();
  if (bid < 144){
    int i = bid*1024 + tid;
    int L = lab[i];
    uint32_t wf = wflag[tid];
    uint32_t m = 0u;
    if (wf != 0xFFFFFFFFu){ L = 1; m = wf; }     // winner override (pos channel)
    else if (L >= 0) m = keys[i];
    if (L < 0){
      out[i] = -1.0f;
    } else {
      int ch = (L == 1) ? 0 : 1;
      if (sel[ch*3+2])           out[i] = (float)L;
      else if (m < sel[ch*3+0])  out[i] = -1.0f;  // provably below the cutoff
      /* else: survivor — written by block 144 */
    }
  } else {
    uint32_t Tf0 = sel[0], all0 = sel[2], Tf1 = sel[3], all1 = sel[5];
    // gather raw survivors (lab as int4, keys scattered; order irrelevant)
    const int4* lab4 = reinterpret_cast<const int4*>(lab);
    for (int j = 0; j < 9; ++j){
      int4 v = lab4[j*1024 + tid];
      int base = (j*1024 + tid) * 16;
      #pragma unroll
      for (int w = 0; w < 4; ++w){
        int wv = (w==0) ? v.x : (w==1) ? v.y : (w==2) ? v.z : v.w;
        #pragma unroll
        for (int b = 0; b < 4; ++b){
          signed char L = (signed char)((wv >> (8*b)) & 0xFF);
          if (L < 0) continue;
          int ch = (L == 1) ? 0 : 1;
          if (ch == 0 ? all0 : all1) continue;
          int idx = base + w*4 + b;
          uint32_t m = keys[idx];
          if (m < (ch == 0 ? Tf0 : Tf1)) continue;
          uint32_t pos = atomicAdd(&nctr[ch], 1u);
          if (pos < 1024u)
            skey[ch*1024 + pos] = ((u64)(m ^ 0x7FFFFFu) << 32) | (uint32_t)idx;
        }
      }
    }
    __syncthreads();
    // patch winner overrides (unique owners only; distinct entries -> race-free)
    if (tid < NGT && respf[tid]){
      uint32_t idx = widx[tid]; signed char rl = wraw[tid]; uint32_t wk = wkey[tid];
      if (rl != 1){
        if (rl == 0 && !all1 && keys[idx] >= Tf1){     // remove from ch1
          uint32_t n1 = nctr[1]; if (n1 > 1024u) n1 = 1024u;
          for (uint32_t p = 0; p < n1; ++p){
            if ((uint32_t)(skey[1024 + p] & 0xFFFFFFFFull) == idx){
              skey[1024 + p] = ~0ull; break;
            }
          }
        }
        if (!all0 && wk >= Tf0){                       // append to ch0
          uint32_t pos = atomicAdd(&nctr[0], 1u);
          if (pos < 1024u)
            skey[pos] = ((u64)(wk ^ 0x7FFFFFu) << 32) | idx;
        }
      }
    }
    __syncthreads();
    // rank-count (sk asc == key desc, idx asc == argsort rank; all sk distinct)
    for (int c = 0; c < 2; ++c){
      if (c == 0 ? all0 : all1) continue;
      uint32_t keep = sel[c*3+1];
      int n = (int)nctr[c]; if (n > 1024) n = 1024;
      float kv = (c == 0) ? 1.0f : 0.0f;
      for (int p = tid; p < n; p += 1024){
        u64 mine = skey[c*1024 + p];
        if (mine == ~0ull) continue;                   // removed sentinel
        uint32_t r = 0;
        for (int q = 0; q < n; ++q) r += (skey[c*1024 + q] < mine) ? 1u : 0u;
        out[(uint32_t)(mine & 0xFFFFFFFFull)] = (r < keep) ? kv : -1.0f;
      }
    }
  }
}

extern "C" void kernel_launch(void* const* d_in, const int* in_sizes, int n_in,
                              void* d_out, int out_size, void* d_ws, size_t ws_size,
                              hipStream_t stream) {
  const float* gt   = (const float*)d_in[1];   // (1,128,4)
  const float* meta = (const float*)d_in[2];   // (1,3) = {H, W, scale}
  float* out = (float*)d_out;                  // labels (147456) + targets (147456*4)
  signed char* lab = (signed char*)d_ws;
  uint32_t* keys = (uint32_t*)((char*)d_ws + N_ANCH);
  uint32_t* ctl  = keys + N_ANCH;

  // jax.random.key(42) = (0,42); partitionable split: key_i = enc(0, i) outputs
  uint32_t a0,a1,b0,b1;
  tf2x32(0u, 42u, 0u, 0u, &a0, &a1);   // k1 (positives)
  tf2x32(0u, 42u, 0u, 1u, &b0, &b1);   // k2 (negatives)

  kA <<<1600, 256, 0, stream>>>(gt, meta, lab, keys, ctl, out, a0, a1, b0, b1);
  kC2<<<145, 1024, 0, stream>>>(lab, keys, out, ctl, a0, a1);
}

// Round 14
// 47.723 us; speedup vs baseline: 1.8383x; 1.8383x over previous
//
#include <hip/hip_runtime.h>
#include <stdint.h>

#define N_ANCH 147456
#define NGT 128

// d_ws layout: lab (N_ANCH B) | keys (N_ANCH u32) | ctl (u32 words below).
// NOTHING needs zero-init: every word read is unconditionally written earlier
// in the same call by a prior kernel (plain disjoint stores, no atomics).
#define W_CNTS   0      // 576 x {cntPos, cntNeg}
#define W_SEL    1152   // 2ch x 4 {Tf, keep, keepAll, pad}  (written by kC blk0, read by kD)
#define W_GMAX2  1160   // 1024 u64 slots (8B-aligned)
#define W_LCNT   3208   // 2 x 576 survivor counts
#define W_LIST   4360   // 2 x 576 x 256 u64 sortkeys
#define MAXSURV  2048

__constant__ float c_base[9][4] = {
  {-84.f,-40.f,99.f,55.f},     // r=0.5 s=8
  {-176.f,-88.f,191.f,103.f},  // r=0.5 s=16
  {-360.f,-184.f,375.f,199.f}, // r=0.5 s=32
  {-56.f,-56.f,71.f,71.f},     // r=1   s=8
  {-120.f,-120.f,135.f,135.f}, // r=1   s=16
  {-248.f,-248.f,263.f,263.f}, // r=1   s=32
  {-36.f,-80.f,51.f,95.f},     // r=2   s=8
  {-80.f,-168.f,95.f,183.f},   // r=2   s=16
  {-168.f,-344.f,183.f,359.f}, // r=2   s=32
};
// exact per-type anchor areas (W*H, integers < 2^24 -> bitwise == __fmul_rn result)
__constant__ float c_areaA[9] = {
  17664.f, 70656.f, 282624.f,
  16384.f, 65536.f, 262144.f,
  15488.f, 61952.f, 247808.f,
};
// extents over all 9 types: x1min=-360 x2max=375 y1min=-344 y2max=359

__host__ __device__ inline uint32_t rotl32(uint32_t v, int d){ return (v<<d)|(v>>(32-d)); }

// JAX Threefry-2x32, 20 rounds
__host__ __device__ inline void tf2x32(uint32_t k0, uint32_t k1, uint32_t x0, uint32_t x1,
                                       uint32_t* o0, uint32_t* o1){
  uint32_t ks0=k0, ks1=k1, ks2=k0^k1^0x1BD11BDAu;
  x0 += ks0; x1 += ks1;
  #define TFR(r) { x0 += x1; x1 = rotl32(x1,(r)); x1 ^= x0; }
  TFR(13) TFR(15) TFR(26) TFR(6)   x0+=ks1; x1+=ks2+1u;
  TFR(17) TFR(29) TFR(16) TFR(24)  x0+=ks2; x1+=ks0+2u;
  TFR(13) TFR(15) TFR(26) TFR(6)   x0+=ks0; x1+=ks1+3u;
  TFR(17) TFR(29) TFR(16) TFR(24)  x0+=ks1; x1+=ks2+4u;
  TFR(13) TFR(15) TFR(26) TFR(6)   x0+=ks2; x1+=ks0+5u;
  #undef TFR
  *o0=x0; *o1=x1;
}

// jax_threefry_partitionable=True: bits(j) = o0^o1 of enc(0,j); key = top 23 bits
__device__ inline uint32_t rand_m23(uint32_t k0, uint32_t k1, uint32_t j){
  uint32_t a, b;
  tf2x32(k0, k1, 0u, j, &a, &b);
  return (a ^ b) >> 9;
}

// kA: blocks <576: per-anchor labels/keys/targets + per-block counts,
//     scanning only the block-relevant gt list (ballot-compacted, index order).
//     blocks >=576: per-(gt,slice) argmax over the gt's overlap window only.
// IoU bitwise-identical to reference path (areas hoisted, same rounding,
// quick-reject ov=+0 == 0/denom).
__global__ __launch_bounds__(256) void kA(const float* __restrict__ gt,
                                          const float* __restrict__ meta,
                                          signed char* __restrict__ lab,
                                          uint32_t* __restrict__ keys,
                                          uint32_t* __restrict__ ctl,
                                          float* __restrict__ out,
                                          uint32_t pk0,uint32_t pk1,
                                          uint32_t nk0,uint32_t nk1){
  int bid = blockIdx.x;
  float W = meta[1], H = meta[0];
  if (bid < 576){
    __shared__ float4 sg[NGT];
    __shared__ float  sB[NGT];
    __shared__ uint32_t slist[NGT];
    __shared__ unsigned long long sball[2];
    __shared__ uint32_t cpk;          // packed (cntPos<<16)|cntNeg, both < 2^16
    if (threadIdx.x == 0) cpk = 0u;
    for (int t = threadIdx.x; t < NGT; t += 256){
      float4 G = reinterpret_cast<const float4*>(gt)[t];
      sg[t] = G;
      sB[t] = __fmul_rn(G.z - G.x + 1.0f, G.w - G.y + 1.0f);
    }
    // block anchor region (all 9 types' extents + 1px float slop)
    int i0 = bid*256, k0 = i0/9, k1 = (i0+255)/9;
    int y0 = k0 >> 7, y1 = k1 >> 7;
    int x0 = (y0==y1) ? (k0 & 127) : 0, x1 = (y0==y1) ? (k1 & 127) : 127;
    float Rxlo = 16.f*x0 - 361.f, Rxhi = 16.f*x1 + 376.f;
    float Rylo = 16.f*y0 - 345.f, Ryhi = 16.f*y1 + 360.f;
    __syncthreads();
    if (threadIdx.x < NGT){
      float4 G = sg[threadIdx.x];
      bool rel = (G.x <= Rxhi) && (G.z >= Rxlo) && (G.y <= Ryhi) && (G.w >= Rylo);
      unsigned long long b = __ballot(rel);
      if ((threadIdx.x & 63) == 0) sball[threadIdx.x >> 6] = b;
    }
    __syncthreads();
    unsigned long long b0 = sball[0], b1 = sball[1];
    if (threadIdx.x < NGT){
      float4 G = sg[threadIdx.x];
      bool rel = (G.x <= Rxhi) && (G.z >= Rxlo) && (G.y <= Ryhi) && (G.w >= Rylo);
      if (rel){
        int lane = threadIdx.x & 63;
        unsigned long long my = (threadIdx.x < 64) ? b0 : b1;
        uint32_t pos = (uint32_t)__popcll(my & ((1ull << lane) - 1ull));
        if (threadIdx.x >= 64) pos += (uint32_t)__popcll(b0);
        slist[pos] = (uint32_t)threadIdx.x;
      }
    }
    __syncthreads();
    int nl = (int)(__popcll(b0) + __popcll(b1));
    int fs;   // first gt index NOT in list (=128 if all in list)
    {
      unsigned long long n0 = ~b0;
      if (n0) fs = __ffsll((long long)n0) - 1;
      else { unsigned long long n1 = ~b1; fs = n1 ? 64 + __ffsll((long long)n1) - 1 : 128; }
    }
    int i = bid*256 + threadIdx.x;
    int k = i / 9; int t9 = i - k*9;
    float sx = 16.0f * (float)(k & 127);
    float sy = 16.0f * (float)(k >> 7);
    float ax1 = c_base[t9][0] + sx, ay1 = c_base[t9][1] + sy;
    float ax2 = c_base[t9][2] + sx, ay2 = c_base[t9][3] + sy;
    float areaA = c_areaA[t9];
    bool inside = (ax1 >= 0.0f) && (ay1 >= 0.0f) && (ax2 < W) && (ay2 < H);
    float best = -1.0f; int arg = 0;   // outside: overlaps all -1 -> argmax 0
    if (inside){
      best = -2.0f;
      for (int li = 0; li < nl; ++li){
        int g = (int)slist[li];
        float4 G = sg[g];
        float iw = fminf(ax2,G.z) - fmaxf(ax1,G.x) + 1.0f;
        float ih = fminf(ay2,G.w) - fmaxf(ay1,G.y) + 1.0f;
        float ov = 0.0f;
        if (iw > 0.0f && ih > 0.0f){
          float inter = __fmul_rn(iw, ih);
          ov = inter / ((areaA + sB[g]) - inter);
        }
        if (ov > best){ best = ov; arg = g; }   // list ascending -> first-occurrence
      }
      if (best < 0.0f){ best = 0.0f; arg = fs; }          // empty list: all-zero row
      else if (best == 0.0f){ arg = (arg < fs) ? arg : fs; } // all-zero row -> idx 0
    }
    signed char L = -1;
    if (best >= 0.7f) L = 1;
    else if (inside && best < 0.3f) L = 0;
    lab[i] = L;
    if (L == 1) keys[i] = rand_m23(pk0,pk1,(uint32_t)i);
    else if (L == 0) keys[i] = rand_m23(nk0,nk1,(uint32_t)i);
    unsigned long long q1 = __ballot(L == 1);
    unsigned long long q0 = __ballot(L == 0);
    if ((threadIdx.x & 63) == 0){
      uint32_t add = ((uint32_t)__popcll(q1) << 16) | (uint32_t)__popcll(q0);
      if (add) atomicAdd(&cpk, add);
    }
    float4 t4 = make_float4(0.f, 0.f, 0.f, 0.f);
    if (inside){
      float4 G = sg[arg];
      float ew = ax2-ax1+1.0f, eh = ay2-ay1+1.0f;
      float ecx = ax1 + 0.5f*ew, ecy = ay1 + 0.5f*eh;
      float gw = G.z-G.x+1.0f, gh = G.w-G.y+1.0f;
      float gcx = G.x + 0.5f*gw, gcy = G.y + 0.5f*gh;
      t4.x = (gcx-ecx)/ew; t4.y = (gcy-ecy)/eh;
      t4.z = logf(gw/ew);  t4.w = logf(gh/eh);
    }
    *reinterpret_cast<float4*>(out + N_ANCH + 4*(size_t)i) = t4;
    __syncthreads();
    if (threadIdx.x == 0){
      uint32_t v = cpk;
      ctl[W_CNTS + 2*bid]     = v >> 16;
      ctl[W_CNTS + 2*bid + 1] = v & 0xFFFFu;
    }
  } else {
    int b2 = bid - 576;
    int g = b2 >> 3, slice = b2 & 7;
    float bx1=gt[4*g], by1=gt[4*g+1], bx2=gt[4*g+2], by2=gt[4*g+3];
    float areaB = __fmul_rn(bx2-bx1+1.0f, by2-by1+1.0f);
    // overlap-possible position window (+1px float slop)
    int pxl = max(0,   (int)ceilf ((bx1 - 377.0f) * 0.0625f));
    int pxh = min(127, (int)floorf((bx2 + 362.0f) * 0.0625f));
    int pyl = max(0,   (int)ceilf ((by1 - 361.0f) * 0.0625f));
    int pyh = min(127, (int)floorf((by2 + 346.0f) * 0.0625f));
    uint32_t Wp = (uint32_t)(pxh - pxl + 1);
    int tot = (int)Wp * (pyh - pyl + 1);
    // magic division: m = ceil(2^22/Wp); exact for Wp<=128, pos<=16383
    uint32_t mdiv = (4194304u + Wp - 1u) / Wp;
    float a0[9],a1[9],a2[9],a3[9];
    #pragma unroll
    for (int t=0;t<9;++t){ a0[t]=c_base[t][0]; a1[t]=c_base[t][1];
                           a2[t]=c_base[t][2]; a3[t]=c_base[t][3]; }
    float best = -2.0f; int bi = 0;
    for (int pos = slice*256 + threadIdx.x; pos < tot; pos += 2048){
      uint32_t dq = (uint32_t)(((unsigned long long)(uint32_t)pos * mdiv) >> 22);
      int py = pyl + (int)dq;
      int px = pxl + (int)((uint32_t)pos - dq * Wp);
      int k = (py << 7) + px;           // ascending in pos -> first-occurrence ties
      float sx = 16.0f * (float)px;
      float sy = 16.0f * (float)py;
      #pragma unroll
      for (int t = 0; t < 9; ++t){
        float ax1=a0[t]+sx, ay1=a1[t]+sy, ax2=a2[t]+sx, ay2=a3[t]+sy;
        bool inside = (ax1 >= 0.0f) && (ay1 >= 0.0f) && (ax2 < W) && (ay2 < H);
        float iw = fminf(ax2,bx2) - fmaxf(ax1,bx1) + 1.0f;
        float ih = fminf(ay2,by2) - fmaxf(ay1,by1) + 1.0f;
        float ov = inside ? 0.0f : -1.0f;
        if (inside && iw > 0.0f && ih > 0.0f){
          float inter = __fmul_rn(iw, ih);
          ov = inter / ((c_areaA[t] + areaB) - inter);
        }
        if (ov > best){ best = ov; bi = k*9 + t; }
      }
    }
    unsigned long long p = 0ull;
    if (best >= 0.0f)
      p = ((unsigned long long)__float_as_uint(best) << 32) | (uint32_t)(~(uint32_t)bi);
    __shared__ unsigned long long sred[256];
    sred[threadIdx.x] = p;
    __syncthreads();
    for (int s = 128; s > 0; s >>= 1){
      if ((int)threadIdx.x < s){
        unsigned long long q = sred[threadIdx.x + s];
        if (q > sred[threadIdx.x]) sred[threadIdx.x] = q;
      }
      __syncthreads();
    }
    if (threadIdx.x == 0)
      reinterpret_cast<unsigned long long*>(ctl + W_GMAX2)[b2] = sred[0];
  }
}

// kC: each block redundantly derives the selection state (winners, counts, Tf)
// from kA's outputs (L2-hot ~13KB), applies winners locally via an LDS flag
// table, writes final labels, appends survivors. Block 0 persists W_SEL for kD.
__global__ __launch_bounds__(256) void kC(const signed char* __restrict__ lab,
                                          const uint32_t* __restrict__ keys,
                                          float* __restrict__ out,
                                          uint32_t* __restrict__ ctl,
                                          uint32_t pk0, uint32_t pk1){
  int tid = threadIdx.x, bid = blockIdx.x;
  __shared__ uint32_t widx[NGT], wkey[NGT], wflag[256];
  __shared__ int sdP, sdN;
  __shared__ unsigned long long red[256];
  __shared__ uint32_t sel[6];     // 2ch x {Tf, keep, keepAll}
  __shared__ uint32_t lcnt[2];
  wflag[tid] = 0xFFFFFFFFu;
  if (tid == 0){ sdP = 0; sdN = 0; lcnt[0] = 0u; lcnt[1] = 0u; }
  if (tid < NGT){
    const unsigned long long* g2 =
      reinterpret_cast<const unsigned long long*>(ctl + W_GMAX2);
    unsigned long long best = 0ull;
    #pragma unroll
    for (int s = 0; s < 8; ++s){
      unsigned long long q = g2[tid*8 + s];
      if (q > best) best = q;
    }
    uint32_t idx = best ? ~(uint32_t)best : 0xFFFFFFFFu;
    widx[tid] = idx;
    wkey[tid] = (idx != 0xFFFFFFFFu) ? rand_m23(pk0, pk1, idx) : 0u;
  }
  // per-block counts (packed u64: no cross-carry, sums < 2^32)
  unsigned long long acc = 0ull;
  for (int b = tid; b < 576; b += 256)
    acc += ((unsigned long long)ctl[W_CNTS + 2*b] << 32) | ctl[W_CNTS + 2*b + 1];
  red[tid] = acc;
  __syncthreads();
  for (int s = 128; s > 0; s >>= 1){
    if (tid < s) red[tid] += red[tid + s];
    __syncthreads();
  }
  if (tid < NGT && widx[tid] != 0xFFFFFFFFu){
    uint32_t idx = widx[tid];
    if ((idx >> 8) == (uint32_t)bid) wflag[idx & 255u] = wkey[tid];
    bool resp = true;                     // dedup: first gt owns a shared winner
    for (int g = 0; g < tid; ++g) if (widx[g] == idx){ resp = false; break; }
    if (resp){
      int oldL = lab[idx];
      if (oldL != 1){ atomicAdd(&sdP, 1); if (oldL == 0) atomicAdd(&sdN, 1); }
    }
  }
  __syncthreads();
  if (tid == 0){
    uint32_t cntP = (uint32_t)(red[0] >> 32) + (uint32_t)sdP;
    uint32_t cntN = (uint32_t)red[0] - (uint32_t)sdN;
    uint32_t keepP = cntP < 128u ? cntP : 128u;
    uint32_t keepN = cntN < (256u - keepP) ? cntN : (256u - keepP);
    uint32_t cnts[2] = {cntP, cntN}, keeps[2] = {keepP, keepN};
    for (int c = 0; c < 2; ++c){
      uint32_t cnt = cnts[c], keep = keeps[c];
      uint32_t all = (keep >= cnt) ? 1u : 0u, Tf = 0u;
      if (!all){
        unsigned long long slack = 2ull * keep;   // mean survivors ~2*keep (>=8 sigma:
        if (slack < cnt)                          // keep>=128 in any non-keepAll ch)
          Tf = (uint32_t)((((unsigned long long)(cnt - slack)) << 23) / cnt);
      }
      sel[c*3+0] = Tf; sel[c*3+1] = keep; sel[c*3+2] = all;
    }
    if (bid == 0){
      for (int c = 0; c < 2; ++c){
        ctl[W_SEL + c*4 + 0] = sel[c*3+0];
        ctl[W_SEL + c*4 + 1] = sel[c*3+1];
        ctl[W_SEL + c*4 + 2] = sel[c*3+2];
      }
    }
  }
  __syncthreads();
  int i = bid*256 + tid;
  int L = lab[i];
  uint32_t wf = wflag[tid];
  uint32_t m = 0u;
  if (wf != 0xFFFFFFFFu){ L = 1; m = wf; }       // winner override (pos channel)
  else if (L >= 0) m = keys[i];
  if (L < 0){
    out[i] = -1.0f;
  } else {
    int ch = (L == 1) ? 0 : 1;
    if (sel[ch*3+2]){
      out[i] = (float)L;
    } else if (m < sel[ch*3+0]){
      out[i] = -1.0f;                      // provably below the cutoff
    } else {
      uint32_t pos = atomicAdd(&lcnt[ch], 1u);
      reinterpret_cast<unsigned long long*>(ctl + W_LIST)
        [(ch*576 + bid)*256 + pos] =
        ((unsigned long long)(m ^ 0x7FFFFFu) << 32) | (uint32_t)i;
    }
  }
  __syncthreads();
  if (tid < 2) ctl[W_LCNT + tid*576 + bid] = lcnt[tid];
}

// kD (1 block x 1024): gather survivors via parallel prefix scan (no
// same-address LDS atomics), rank-count (no sort), write labels.
// sk asc == (key desc, idx asc) == argsort rank order; all sk distinct.
__global__ __launch_bounds__(1024) void kD(float* __restrict__ out,
                                           uint32_t* __restrict__ ctl){
  int tid = threadIdx.x;
  __shared__ unsigned long long skey[MAXSURV];   // 16 KB
  __shared__ uint32_t scan[1024];                // 4 KB
  for (int c = 0; c < 2; ++c){
    uint32_t keep    = ctl[W_SEL + c*4 + 1];
    uint32_t keepAll = ctl[W_SEL + c*4 + 2];
    if (!keepAll){
      uint32_t cnum = (tid < 576) ? ctl[W_LCNT + c*576 + tid] : 0u;
      scan[tid] = cnum;
      __syncthreads();
      // Hillis-Steele inclusive scan over 1024 entries
      for (int off = 1; off < 1024; off <<= 1){
        uint32_t v = (tid >= off) ? scan[tid - off] : 0u;
        __syncthreads();
        scan[tid] += v;
        __syncthreads();
      }
      int n = (int)scan[1023]; if (n > MAXSURV) n = MAXSURV;
      if (cnum){
        uint32_t base = scan[tid] - cnum;   // exclusive prefix
        const unsigned long long* list =
          reinterpret_cast<const unsigned long long*>(ctl + W_LIST)
          + (size_t)(c*576 + tid)*256;
        for (uint32_t j = 0; j < cnum; ++j){
          uint32_t p = base + j;
          if (p < (uint32_t)MAXSURV) skey[p] = list[j];
        }
      }
      __syncthreads();
      float kv = (c == 0) ? 1.0f : 0.0f;
      for (int p = tid; p < n; p += 1024){
        unsigned long long mine = skey[p];
        uint32_t r = 0;
        for (int j = 0; j < n; ++j) r += (skey[j] < mine) ? 1u : 0u;  // LDS broadcast
        uint32_t idx = (uint32_t)(mine & 0xFFFFFFFFull);
        out[idx] = (r < keep) ? kv : -1.0f;
      }
    }
    __syncthreads();
  }
}

extern "C" void kernel_launch(void* const* d_in, const int* in_sizes, int n_in,
                              void* d_out, int out_size, void* d_ws, size_t ws_size,
                              hipStream_t stream) {
  const float* gt   = (const float*)d_in[1];   // (1,128,4)
  const float* meta = (const float*)d_in[2];   // (1,3) = {H, W, scale}
  float* out = (float*)d_out;                  // labels (147456) + targets (147456*4)
  signed char* lab = (signed char*)d_ws;
  uint32_t* keys = (uint32_t*)((char*)d_ws + N_ANCH);
  uint32_t* ctl  = keys + N_ANCH;

  // jax.random.key(42) = (0,42); partitionable split: key_i = enc(0, i) outputs
  uint32_t a0,a1,b0,b1;
  tf2x32(0u, 42u, 0u, 0u, &a0, &a1);   // k1 (positives)
  tf2x32(0u, 42u, 0u, 1u, &b0, &b1);   // k2 (negatives)

  kA<<<1600, 256, 0, stream>>>(gt, meta, lab, keys, ctl, out, a0, a1, b0, b1);
  kC<<<576, 256, 0, stream>>>(lab, keys, out, ctl, a0, a1);
  kD<<<1, 1024, 0, stream>>>(out, ctl);
}

// Round 15
// 45.330 us; speedup vs baseline: 1.9353x; 1.0528x over previous
//
#include <hip/hip_runtime.h>
#include <stdint.h>

#define N_ANCH 147456
#define NGT 128

// d_ws layout: lab (N_ANCH B) | keys (N_ANCH u32) | ctl (u32 words below).
// NOTHING needs zero-init: every word read is unconditionally written earlier
// in the same call by a prior kernel (plain disjoint stores, no atomics).
#define W_CNTS   0      // 576 x {cntPos, cntNeg}
#define W_SEL    1152   // 2ch x 4 {Tf, keep, keepAll, pad}  (written by kC blk0, read by kD)
#define W_GMAX2  1160   // 512 u64 slots (8B-aligned)
#define W_LCNT   3208   // 2 x 576 survivor counts
#define W_LIST   4360   // 2 x 576 x 256 u64 sortkeys
#define MAXSURV  2048

__constant__ float c_base[9][4] = {
  {-84.f,-40.f,99.f,55.f},     // r=0.5 s=8
  {-176.f,-88.f,191.f,103.f},  // r=0.5 s=16
  {-360.f,-184.f,375.f,199.f}, // r=0.5 s=32
  {-56.f,-56.f,71.f,71.f},     // r=1   s=8
  {-120.f,-120.f,135.f,135.f}, // r=1   s=16
  {-248.f,-248.f,263.f,263.f}, // r=1   s=32
  {-36.f,-80.f,51.f,95.f},     // r=2   s=8
  {-80.f,-168.f,95.f,183.f},   // r=2   s=16
  {-168.f,-344.f,183.f,359.f}, // r=2   s=32
};
// exact per-type anchor areas (W*H, integers < 2^24 -> bitwise == __fmul_rn result)
__constant__ float c_areaA[9] = {
  17664.f, 70656.f, 282624.f,
  16384.f, 65536.f, 262144.f,
  15488.f, 61952.f, 247808.f,
};
// extents over all 9 types: x1min=-360 x2max=375 y1min=-344 y2max=359

__host__ __device__ inline uint32_t rotl32(uint32_t v, int d){ return (v<<d)|(v>>(32-d)); }

// JAX Threefry-2x32, 20 rounds
__host__ __device__ inline void tf2x32(uint32_t k0, uint32_t k1, uint32_t x0, uint32_t x1,
                                       uint32_t* o0, uint32_t* o1){
  uint32_t ks0=k0, ks1=k1, ks2=k0^k1^0x1BD11BDAu;
  x0 += ks0; x1 += ks1;
  #define TFR(r) { x0 += x1; x1 = rotl32(x1,(r)); x1 ^= x0; }
  TFR(13) TFR(15) TFR(26) TFR(6)   x0+=ks1; x1+=ks2+1u;
  TFR(17) TFR(29) TFR(16) TFR(24)  x0+=ks2; x1+=ks0+2u;
  TFR(13) TFR(15) TFR(26) TFR(6)   x0+=ks0; x1+=ks1+3u;
  TFR(17) TFR(29) TFR(16) TFR(24)  x0+=ks1; x1+=ks2+4u;
  TFR(13) TFR(15) TFR(26) TFR(6)   x0+=ks2; x1+=ks0+5u;
  #undef TFR
  *o0=x0; *o1=x1;
}

// jax_threefry_partitionable=True: bits(j) = o0^o1 of enc(0,j); key = top 23 bits
__device__ inline uint32_t rand_m23(uint32_t k0, uint32_t k1, uint32_t j){
  uint32_t a, b;
  tf2x32(k0, k1, 0u, j, &a, &b);
  return (a ^ b) >> 9;
}

// kA: blocks <576: per-anchor labels/keys/targets + per-block counts, scanning
//     only the WAVE-relevant gt list (per-wave ballot-compacted, index order —
//     a wave spans ~7 grid cols so the x-filter is tight; same margins).
//     blocks >=576: per-(gt,slice) argmax over the gt's overlap window (4 slices).
// IoU bitwise-identical to reference path (areas hoisted, same rounding,
// quick-reject ov=+0 == 0/denom). Argmax edge cases:
//  - all-zero row: best==0 -> arg=min(list[0],fs)==0; empty list -> (0,fs).
//  - gt outside wave window ==> ov==0 for every anchor in the wave (margins
//    cover all 9 type extents +1px slop) -> list is exact for ov>0.
__global__ __launch_bounds__(256) void kA(const float* __restrict__ gt,
                                          const float* __restrict__ meta,
                                          signed char* __restrict__ lab,
                                          uint32_t* __restrict__ keys,
                                          uint32_t* __restrict__ ctl,
                                          float* __restrict__ out,
                                          uint32_t pk0,uint32_t pk1,
                                          uint32_t nk0,uint32_t nk1){
  int bid = blockIdx.x;
  float W = meta[1], H = meta[0];
  if (bid < 576){
    __shared__ float4 sg[NGT];
    __shared__ float  sB[NGT];
    __shared__ uint32_t slist[4][NGT];   // per-wave relevant-gt lists
    __shared__ uint32_t cpk;             // packed (cntPos<<16)|cntNeg
    if (threadIdx.x == 0) cpk = 0u;
    for (int t = threadIdx.x; t < NGT; t += 256){
      float4 G = reinterpret_cast<const float4*>(gt)[t];
      sg[t] = G;
      sB[t] = __fmul_rn(G.z - G.x + 1.0f, G.w - G.y + 1.0f);
    }
    __syncthreads();
    int wv = threadIdx.x >> 6, lane = threadIdx.x & 63;
    // wave anchor region (all 9 types' extents + 1px float slop)
    int i0w = bid*256 + wv*64;
    int k0w = i0w/9, k1w = (i0w+63)/9;
    int y0 = k0w >> 7, y1 = k1w >> 7;
    int x0 = (y0==y1) ? (k0w & 127) : 0, x1 = (y0==y1) ? (k1w & 127) : 127;
    float Rxlo = 16.f*x0 - 361.f, Rxhi = 16.f*x1 + 376.f;
    float Rylo = 16.f*y0 - 345.f, Ryhi = 16.f*y1 + 360.f;
    float4 Ga = sg[lane], Gb = sg[lane+64];
    bool r0 = (Ga.x <= Rxhi) && (Ga.z >= Rxlo) && (Ga.y <= Ryhi) && (Ga.w >= Rylo);
    bool r1 = (Gb.x <= Rxhi) && (Gb.z >= Rxlo) && (Gb.y <= Ryhi) && (Gb.w >= Rylo);
    unsigned long long m0 = __ballot(r0), m1 = __ballot(r1);
    unsigned long long lt = (1ull << lane) - 1ull;
    uint32_t c0n = (uint32_t)__popcll(m0);
    if (r0) slist[wv][(uint32_t)__popcll(m0 & lt)] = (uint32_t)lane;
    if (r1) slist[wv][c0n + (uint32_t)__popcll(m1 & lt)] = (uint32_t)(64 + lane);
    int nl = (int)(c0n + (uint32_t)__popcll(m1));
    int fs;   // first gt index NOT in list (=128 if all in list)
    {
      unsigned long long n0 = ~m0;
      if (n0) fs = __ffsll((long long)n0) - 1;
      else { unsigned long long n1 = ~m1; fs = n1 ? 64 + __ffsll((long long)n1) - 1 : 128; }
    }
    __syncthreads();   // safety: list build complete (wave-local, but cheap)
    int i = bid*256 + threadIdx.x;
    int k = i / 9; int t9 = i - k*9;
    float sx = 16.0f * (float)(k & 127);
    float sy = 16.0f * (float)(k >> 7);
    float ax1 = c_base[t9][0] + sx, ay1 = c_base[t9][1] + sy;
    float ax2 = c_base[t9][2] + sx, ay2 = c_base[t9][3] + sy;
    float areaA = c_areaA[t9];
    bool inside = (ax1 >= 0.0f) && (ay1 >= 0.0f) && (ax2 < W) && (ay2 < H);
    float best = -1.0f; int arg = 0;   // outside: overlaps all -1 -> argmax 0
    if (inside){
      best = -2.0f;
      for (int li = 0; li < nl; ++li){
        int g = (int)slist[wv][li];
        float4 G = sg[g];
        float iw = fminf(ax2,G.z) - fmaxf(ax1,G.x) + 1.0f;
        float ih = fminf(ay2,G.w) - fmaxf(ay1,G.y) + 1.0f;
        float ov = 0.0f;
        if (iw > 0.0f && ih > 0.0f){
          float inter = __fmul_rn(iw, ih);
          ov = inter / ((areaA + sB[g]) - inter);
        }
        if (ov > best){ best = ov; arg = g; }   // list ascending -> first-occurrence
      }
      if (best < 0.0f){ best = 0.0f; arg = fs; }          // empty list: all-zero row
      else if (best == 0.0f){ arg = (arg < fs) ? arg : fs; } // all-zero row -> idx 0
    }
    signed char L = -1;
    if (best >= 0.7f) L = 1;
    else if (inside && best < 0.3f) L = 0;
    lab[i] = L;
    if (L == 1) keys[i] = rand_m23(pk0,pk1,(uint32_t)i);
    else if (L == 0) keys[i] = rand_m23(nk0,nk1,(uint32_t)i);
    unsigned long long q1 = __ballot(L == 1);
    unsigned long long q0 = __ballot(L == 0);
    if (lane == 0){
      uint32_t add = ((uint32_t)__popcll(q1) << 16) | (uint32_t)__popcll(q0);
      if (add) atomicAdd(&cpk, add);
    }
    float4 t4 = make_float4(0.f, 0.f, 0.f, 0.f);
    if (inside){
      float4 G = sg[arg];
      float ew = ax2-ax1+1.0f, eh = ay2-ay1+1.0f;
      float ecx = ax1 + 0.5f*ew, ecy = ay1 + 0.5f*eh;
      float gw = G.z-G.x+1.0f, gh = G.w-G.y+1.0f;
      float gcx = G.x + 0.5f*gw, gcy = G.y + 0.5f*gh;
      t4.x = (gcx-ecx)/ew; t4.y = (gcy-ecy)/eh;
      t4.z = logf(gw/ew);  t4.w = logf(gh/eh);
    }
    *reinterpret_cast<float4*>(out + N_ANCH + 4*(size_t)i) = t4;
    __syncthreads();
    if (threadIdx.x == 0){
      uint32_t v = cpk;
      ctl[W_CNTS + 2*bid]     = v >> 16;
      ctl[W_CNTS + 2*bid + 1] = v & 0xFFFFu;
    }
  } else {
    int b2 = bid - 576;
    int g = b2 >> 2, slice = b2 & 3;      // 4 slices per gt
    float bx1=gt[4*g], by1=gt[4*g+1], bx2=gt[4*g+2], by2=gt[4*g+3];
    float areaB = __fmul_rn(bx2-bx1+1.0f, by2-by1+1.0f);
    // overlap-possible position window (+1px float slop)
    int pxl = max(0,   (int)ceilf ((bx1 - 377.0f) * 0.0625f));
    int pxh = min(127, (int)floorf((bx2 + 362.0f) * 0.0625f));
    int pyl = max(0,   (int)ceilf ((by1 - 361.0f) * 0.0625f));
    int pyh = min(127, (int)floorf((by2 + 346.0f) * 0.0625f));
    uint32_t Wp = (uint32_t)(pxh - pxl + 1);
    int tot = (int)Wp * (pyh - pyl + 1);
    // magic division: m = ceil(2^22/Wp); exact for Wp<=128, pos<=16383
    uint32_t mdiv = (4194304u + Wp - 1u) / Wp;
    float a0[9],a1[9],a2[9],a3[9];
    #pragma unroll
    for (int t=0;t<9;++t){ a0[t]=c_base[t][0]; a1[t]=c_base[t][1];
                           a2[t]=c_base[t][2]; a3[t]=c_base[t][3]; }
    float best = -2.0f; int bi = 0;
    for (int pos = slice*256 + threadIdx.x; pos < tot; pos += 1024){
      uint32_t dq = (uint32_t)(((unsigned long long)(uint32_t)pos * mdiv) >> 22);
      int py = pyl + (int)dq;
      int px = pxl + (int)((uint32_t)pos - dq * Wp);
      int k = (py << 7) + px;           // ascending in pos -> first-occurrence ties
      float sx = 16.0f * (float)px;
      float sy = 16.0f * (float)py;
      #pragma unroll
      for (int t = 0; t < 9; ++t){
        float ax1=a0[t]+sx, ay1=a1[t]+sy, ax2=a2[t]+sx, ay2=a3[t]+sy;
        bool inside = (ax1 >= 0.0f) && (ay1 >= 0.0f) && (ax2 < W) && (ay2 < H);
        float iw = fminf(ax2,bx2) - fmaxf(ax1,bx1) + 1.0f;
        float ih = fminf(ay2,by2) - fmaxf(ay1,by1) + 1.0f;
        float ov = inside ? 0.0f : -1.0f;
        if (inside && iw > 0.0f && ih > 0.0f){
          float inter = __fmul_rn(iw, ih);
          ov = inter / ((c_areaA[t] + areaB) - inter);
        }
        if (ov > best){ best = ov; bi = k*9 + t; }
      }
    }
    unsigned long long p = 0ull;
    if (best >= 0.0f)
      p = ((unsigned long long)__float_as_uint(best) << 32) | (uint32_t)(~(uint32_t)bi);
    __shared__ unsigned long long sred[256];
    sred[threadIdx.x] = p;
    __syncthreads();
    for (int s = 128; s > 0; s >>= 1){
      if ((int)threadIdx.x < s){
        unsigned long long q = sred[threadIdx.x + s];
        if (q > sred[threadIdx.x]) sred[threadIdx.x] = q;
      }
      __syncthreads();
    }
    if (threadIdx.x == 0)
      reinterpret_cast<unsigned long long*>(ctl + W_GMAX2)[b2] = sred[0];
  }
}

// kC: each block redundantly derives the selection state (winners, counts, Tf)
// from kA's outputs (L2-hot ~7KB), applies winners locally via an LDS flag
// table, writes final labels, appends survivors. Block 0 persists W_SEL for kD.
__global__ __launch_bounds__(256) void kC(const signed char* __restrict__ lab,
                                          const uint32_t* __restrict__ keys,
                                          float* __restrict__ out,
                                          uint32_t* __restrict__ ctl,
                                          uint32_t pk0, uint32_t pk1){
  int tid = threadIdx.x, bid = blockIdx.x;
  __shared__ uint32_t widx[NGT], wkey[NGT], wflag[256];
  __shared__ int sdP, sdN;
  __shared__ unsigned long long red[256];
  __shared__ uint32_t sel[6];     // 2ch x {Tf, keep, keepAll}
  __shared__ uint32_t lcnt[2];
  wflag[tid] = 0xFFFFFFFFu;
  if (tid == 0){ sdP = 0; sdN = 0; lcnt[0] = 0u; lcnt[1] = 0u; }
  if (tid < NGT){
    const unsigned long long* g2 =
      reinterpret_cast<const unsigned long long*>(ctl + W_GMAX2);
    unsigned long long best = 0ull;
    #pragma unroll
    for (int s = 0; s < 4; ++s){
      unsigned long long q = g2[tid*4 + s];
      if (q > best) best = q;
    }
    uint32_t idx = best ? ~(uint32_t)best : 0xFFFFFFFFu;
    widx[tid] = idx;
    wkey[tid] = (idx != 0xFFFFFFFFu) ? rand_m23(pk0, pk1, idx) : 0u;
  }
  // per-block counts (packed u64: no cross-carry, sums < 2^32)
  unsigned long long acc = 0ull;
  for (int b = tid; b < 576; b += 256)
    acc += ((unsigned long long)ctl[W_CNTS + 2*b] << 32) | ctl[W_CNTS + 2*b + 1];
  red[tid] = acc;
  __syncthreads();
  for (int s = 128; s > 0; s >>= 1){
    if (tid < s) red[tid] += red[tid + s];
    __syncthreads();
  }
  if (tid < NGT && widx[tid] != 0xFFFFFFFFu){
    uint32_t idx = widx[tid];
    if ((idx >> 8) == (uint32_t)bid) wflag[idx & 255u] = wkey[tid];
    bool resp = true;                     // dedup: first gt owns a shared winner
    for (int g = 0; g < tid; ++g) if (widx[g] == idx){ resp = false; break; }
    if (resp){
      int oldL = lab[idx];
      if (oldL != 1){ atomicAdd(&sdP, 1); if (oldL == 0) atomicAdd(&sdN, 1); }
    }
  }
  __syncthreads();
  if (tid == 0){
    uint32_t cntP = (uint32_t)(red[0] >> 32) + (uint32_t)sdP;
    uint32_t cntN = (uint32_t)red[0] - (uint32_t)sdN;
    uint32_t keepP = cntP < 128u ? cntP : 128u;
    uint32_t keepN = cntN < (256u - keepP) ? cntN : (256u - keepP);
    uint32_t cnts[2] = {cntP, cntN}, keeps[2] = {keepP, keepN};
    for (int c = 0; c < 2; ++c){
      uint32_t cnt = cnts[c], keep = keeps[c];
      uint32_t all = (keep >= cnt) ? 1u : 0u, Tf = 0u;
      if (!all){
        unsigned long long slack = 2ull * keep;   // mean survivors ~2*keep (>=8 sigma:
        if (slack < cnt)                          // keep>=128 in any non-keepAll ch)
          Tf = (uint32_t)((((unsigned long long)(cnt - slack)) << 23) / cnt);
      }
      sel[c*3+0] = Tf; sel[c*3+1] = keep; sel[c*3+2] = all;
    }
    if (bid == 0){
      for (int c = 0; c < 2; ++c){
        ctl[W_SEL + c*4 + 0] = sel[c*3+0];
        ctl[W_SEL + c*4 + 1] = sel[c*3+1];
        ctl[W_SEL + c*4 + 2] = sel[c*3+2];
      }
    }
  }
  __syncthreads();
  int i = bid*256 + tid;
  int L = lab[i];
  uint32_t wf = wflag[tid];
  uint32_t m = 0u;
  if (wf != 0xFFFFFFFFu){ L = 1; m = wf; }       // winner override (pos channel)
  else if (L >= 0) m = keys[i];
  if (L < 0){
    out[i] = -1.0f;
  } else {
    int ch = (L == 1) ? 0 : 1;
    if (sel[ch*3+2]){
      out[i] = (float)L;
    } else if (m < sel[ch*3+0]){
      out[i] = -1.0f;                      // provably below the cutoff
    } else {
      uint32_t pos = atomicAdd(&lcnt[ch], 1u);
      reinterpret_cast<unsigned long long*>(ctl + W_LIST)
        [(ch*576 + bid)*256 + pos] =
        ((unsigned long long)(m ^ 0x7FFFFFu) << 32) | (uint32_t)i;
    }
  }
  __syncthreads();
  if (tid < 2) ctl[W_LCNT + tid*576 + bid] = lcnt[tid];
}

// kD (1 block x 1024): gather survivors via parallel prefix scan (no
// same-address LDS atomics), rank-count (no sort), write labels.
// sk asc == (key desc, idx asc) == argsort rank order; all sk distinct.
__global__ __launch_bounds__(1024) void kD(float* __restrict__ out,
                                           uint32_t* __restrict__ ctl){
  int tid = threadIdx.x;
  __shared__ unsigned long long skey[MAXSURV];   // 16 KB
  __shared__ uint32_t scan[1024];                // 4 KB
  for (int c = 0; c < 2; ++c){
    uint32_t keep    = ctl[W_SEL + c*4 + 1];
    uint32_t keepAll = ctl[W_SEL + c*4 + 2];
    if (!keepAll){
      uint32_t cnum = (tid < 576) ? ctl[W_LCNT + c*576 + tid] : 0u;
      scan[tid] = cnum;
      __syncthreads();
      // Hillis-Steele inclusive scan over 1024 entries
      for (int off = 1; off < 1024; off <<= 1){
        uint32_t v = (tid >= off) ? scan[tid - off] : 0u;
        __syncthreads();
        scan[tid] += v;
        __syncthreads();
      }
      int n = (int)scan[1023]; if (n > MAXSURV) n = MAXSURV;
      if (cnum){
        uint32_t base = scan[tid] - cnum;   // exclusive prefix
        const unsigned long long* list =
          reinterpret_cast<const unsigned long long*>(ctl + W_LIST)
          + (size_t)(c*576 + tid)*256;
        for (uint32_t j = 0; j < cnum; ++j){
          uint32_t p = base + j;
          if (p < (uint32_t)MAXSURV) skey[p] = list[j];
        }
      }
      __syncthreads();
      float kv = (c == 0) ? 1.0f : 0.0f;
      for (int p = tid; p < n; p += 1024){
        unsigned long long mine = skey[p];
        uint32_t r = 0;
        for (int j = 0; j < n; ++j) r += (skey[j] < mine) ? 1u : 0u;  // LDS broadcast
        uint32_t idx = (uint32_t)(mine & 0xFFFFFFFFull);
        out[idx] = (r < keep) ? kv : -1.0f;
      }
    }
    __syncthreads();
  }
}

extern "C" void kernel_launch(void* const* d_in, const int* in_sizes, int n_in,
                              void* d_out, int out_size, void* d_ws, size_t ws_size,
                              hipStream_t stream) {
  const float* gt   = (const float*)d_in[1];   // (1,128,4)
  const float* meta = (const float*)d_in[2];   // (1,3) = {H, W, scale}
  float* out = (float*)d_out;                  // labels (147456) + targets (147456*4)
  signed char* lab = (signed char*)d_ws;
  uint32_t* keys = (uint32_t*)((char*)d_ws + N_ANCH);
  uint32_t* ctl  = keys + N_ANCH;

  // jax.random.key(42) = (0,42); partitionable split: key_i = enc(0, i) outputs
  uint32_t a0,a1,b0,b1;
  tf2x32(0u, 42u, 0u, 0u, &a0, &a1);   // k1 (positives)
  tf2x32(0u, 42u, 0u, 1u, &b0, &b1);   // k2 (negatives)

  kA<<<1088, 256, 0, stream>>>(gt, meta, lab, keys, ctl, out, a0, a1, b0, b1);
  kC<<<576, 256, 0, stream>>>(lab, keys, out, ctl, a0, a1);
  kD<<<1, 1024, 0, stream>>>(out, ctl);
}

// Round 16
// 44.935 us; speedup vs baseline: 1.9523x; 1.0088x over previous
//
#include <hip/hip_runtime.h>
#include <stdint.h>

#define N_ANCH 147456
#define NGT 128

// d_ws layout: lab (N_ANCH B) | keys (N_ANCH u32) | ctl (u32 words below).
// NOTHING needs zero-init: every word read is unconditionally written earlier
// in the same call by a prior kernel (plain disjoint stores, no atomics).
#define W_CNTS   0      // 576 x {cntPos, cntNeg}
#define W_SEL    1152   // 2ch x 4 {Tf, keep, keepAll, pad}  (written by kC blk0, read by kD)
#define W_GMAX2  1160   // 512 u64 slots (8B-aligned)
#define W_LCNT   3208   // 2 x 576 survivor counts
#define W_LIST   4360   // 2 x 576 x 256 u64 sortkeys
#define MAXSURV  2048

typedef unsigned long long u64;

__constant__ float c_base[9][4] = {
  {-84.f,-40.f,99.f,55.f},     // r=0.5 s=8
  {-176.f,-88.f,191.f,103.f},  // r=0.5 s=16
  {-360.f,-184.f,375.f,199.f}, // r=0.5 s=32
  {-56.f,-56.f,71.f,71.f},     // r=1   s=8
  {-120.f,-120.f,135.f,135.f}, // r=1   s=16
  {-248.f,-248.f,263.f,263.f}, // r=1   s=32
  {-36.f,-80.f,51.f,95.f},     // r=2   s=8
  {-80.f,-168.f,95.f,183.f},   // r=2   s=16
  {-168.f,-344.f,183.f,359.f}, // r=2   s=32
};
// exact per-type anchor areas (W*H, integers < 2^24 -> bitwise == __fmul_rn result)
__constant__ float c_areaA[9] = {
  17664.f, 70656.f, 282624.f,
  16384.f, 65536.f, 262144.f,
  15488.f, 61952.f, 247808.f,
};
// extents over all 9 types: x1min=-360 x2max=375 y1min=-344 y2max=359

__host__ __device__ inline uint32_t rotl32(uint32_t v, int d){ return (v<<d)|(v>>(32-d)); }

// JAX Threefry-2x32, 20 rounds
__host__ __device__ inline void tf2x32(uint32_t k0, uint32_t k1, uint32_t x0, uint32_t x1,
                                       uint32_t* o0, uint32_t* o1){
  uint32_t ks0=k0, ks1=k1, ks2=k0^k1^0x1BD11BDAu;
  x0 += ks0; x1 += ks1;
  #define TFR(r) { x0 += x1; x1 = rotl32(x1,(r)); x1 ^= x0; }
  TFR(13) TFR(15) TFR(26) TFR(6)   x0+=ks1; x1+=ks2+1u;
  TFR(17) TFR(29) TFR(16) TFR(24)  x0+=ks2; x1+=ks0+2u;
  TFR(13) TFR(15) TFR(26) TFR(6)   x0+=ks0; x1+=ks1+3u;
  TFR(17) TFR(29) TFR(16) TFR(24)  x0+=ks1; x1+=ks2+4u;
  TFR(13) TFR(15) TFR(26) TFR(6)   x0+=ks2; x1+=ks0+5u;
  #undef TFR
  *o0=x0; *o1=x1;
}

// jax_threefry_partitionable=True: bits(j) = o0^o1 of enc(0,j); key = top 23 bits
__device__ inline uint32_t rand_m23(uint32_t k0, uint32_t k1, uint32_t j){
  uint32_t a, b;
  tf2x32(k0, k1, 0u, j, &a, &b);
  return (a ^ b) >> 9;
}

// kA: blocks <576: per-anchor labels/keys/targets + per-block counts, scanning
//     only the WAVE-relevant gt list (per-wave ballot-compacted, index order;
//     wave-local LDS => no barrier needed after list build).
//     blocks >=576: per-(gt,slice) argmax over the gt's overlap window (4 slices).
// IoU bitwise-identical to reference path (areas hoisted, same rounding,
// quick-reject ov=+0 == 0/denom). Argmax edge cases as before (fs logic).
__global__ __launch_bounds__(256) void kA(const float* __restrict__ gt,
                                          const float* __restrict__ meta,
                                          signed char* __restrict__ lab,
                                          uint32_t* __restrict__ keys,
                                          uint32_t* __restrict__ ctl,
                                          float* __restrict__ out,
                                          uint32_t pk0,uint32_t pk1,
                                          uint32_t nk0,uint32_t nk1){
  int bid = blockIdx.x;
  float W = meta[1], H = meta[0];
  if (bid < 576){
    __shared__ float4 sg[NGT];
    __shared__ float  sB[NGT];
    __shared__ uint32_t slist[4][NGT];   // per-wave relevant-gt lists (wave-local)
    __shared__ uint32_t cpk;             // packed (cntPos<<16)|cntNeg
    if (threadIdx.x == 0) cpk = 0u;
    for (int t = threadIdx.x; t < NGT; t += 256){
      float4 G = reinterpret_cast<const float4*>(gt)[t];
      sg[t] = G;
      sB[t] = __fmul_rn(G.z - G.x + 1.0f, G.w - G.y + 1.0f);
    }
    __syncthreads();
    int wv = threadIdx.x >> 6, lane = threadIdx.x & 63;
    // wave anchor region (all 9 types' extents + 1px float slop)
    int i0w = bid*256 + wv*64;
    int k0w = i0w/9, k1w = (i0w+63)/9;
    int y0 = k0w >> 7, y1 = k1w >> 7;
    int x0 = (y0==y1) ? (k0w & 127) : 0, x1 = (y0==y1) ? (k1w & 127) : 127;
    float Rxlo = 16.f*x0 - 361.f, Rxhi = 16.f*x1 + 376.f;
    float Rylo = 16.f*y0 - 345.f, Ryhi = 16.f*y1 + 360.f;
    float4 Ga = sg[lane], Gb = sg[lane+64];
    bool r0 = (Ga.x <= Rxhi) && (Ga.z >= Rxlo) && (Ga.y <= Ryhi) && (Ga.w >= Rylo);
    bool r1 = (Gb.x <= Rxhi) && (Gb.z >= Rxlo) && (Gb.y <= Ryhi) && (Gb.w >= Rylo);
    unsigned long long m0 = __ballot(r0), m1 = __ballot(r1);
    unsigned long long lt = (1ull << lane) - 1ull;
    uint32_t c0n = (uint32_t)__popcll(m0);
    if (r0) slist[wv][(uint32_t)__popcll(m0 & lt)] = (uint32_t)lane;
    if (r1) slist[wv][c0n + (uint32_t)__popcll(m1 & lt)] = (uint32_t)(64 + lane);
    int nl = (int)(c0n + (uint32_t)__popcll(m1));
    int fs;   // first gt index NOT in list (=128 if all in list)
    {
      unsigned long long n0 = ~m0;
      if (n0) fs = __ffsll((long long)n0) - 1;
      else { unsigned long long n1 = ~m1; fs = n1 ? 64 + __ffsll((long long)n1) - 1 : 128; }
    }
    // no barrier: slist[wv] is produced and consumed by the same wave
    int i = bid*256 + threadIdx.x;
    int k = i / 9; int t9 = i - k*9;
    float sx = 16.0f * (float)(k & 127);
    float sy = 16.0f * (float)(k >> 7);
    float ax1 = c_base[t9][0] + sx, ay1 = c_base[t9][1] + sy;
    float ax2 = c_base[t9][2] + sx, ay2 = c_base[t9][3] + sy;
    float areaA = c_areaA[t9];
    bool inside = (ax1 >= 0.0f) && (ay1 >= 0.0f) && (ax2 < W) && (ay2 < H);
    float best = -1.0f; int arg = 0;   // outside: overlaps all -1 -> argmax 0
    if (inside){
      best = -2.0f;
      for (int li = 0; li < nl; ++li){
        int g = (int)slist[wv][li];
        float4 G = sg[g];
        float iw = fminf(ax2,G.z) - fmaxf(ax1,G.x) + 1.0f;
        float ih = fminf(ay2,G.w) - fmaxf(ay1,G.y) + 1.0f;
        float ov = 0.0f;
        if (iw > 0.0f && ih > 0.0f){
          float inter = __fmul_rn(iw, ih);
          ov = inter / ((areaA + sB[g]) - inter);
        }
        if (ov > best){ best = ov; arg = g; }   // list ascending -> first-occurrence
      }
      if (best < 0.0f){ best = 0.0f; arg = fs; }          // empty list: all-zero row
      else if (best == 0.0f){ arg = (arg < fs) ? arg : fs; } // all-zero row -> idx 0
    }
    signed char L = -1;
    if (best >= 0.7f) L = 1;
    else if (inside && best < 0.3f) L = 0;
    lab[i] = L;
    if (L == 1) keys[i] = rand_m23(pk0,pk1,(uint32_t)i);
    else if (L == 0) keys[i] = rand_m23(nk0,nk1,(uint32_t)i);
    unsigned long long q1 = __ballot(L == 1);
    unsigned long long q0 = __ballot(L == 0);
    if (lane == 0){
      uint32_t add = ((uint32_t)__popcll(q1) << 16) | (uint32_t)__popcll(q0);
      if (add) atomicAdd(&cpk, add);
    }
    float4 t4 = make_float4(0.f, 0.f, 0.f, 0.f);
    if (inside){
      float4 G = sg[arg];
      float ew = ax2-ax1+1.0f, eh = ay2-ay1+1.0f;
      float ecx = ax1 + 0.5f*ew, ecy = ay1 + 0.5f*eh;
      float gw = G.z-G.x+1.0f, gh = G.w-G.y+1.0f;
      float gcx = G.x + 0.5f*gw, gcy = G.y + 0.5f*gh;
      t4.x = (gcx-ecx)/ew; t4.y = (gcy-ecy)/eh;
      t4.z = logf(gw/ew);  t4.w = logf(gh/eh);
    }
    *reinterpret_cast<float4*>(out + N_ANCH + 4*(size_t)i) = t4;
    __syncthreads();
    if (threadIdx.x == 0){
      uint32_t v = cpk;
      ctl[W_CNTS + 2*bid]     = v >> 16;
      ctl[W_CNTS + 2*bid + 1] = v & 0xFFFFu;
    }
  } else {
    int b2 = bid - 576;
    int g = b2 >> 2, slice = b2 & 3;      // 4 slices per gt
    float bx1=gt[4*g], by1=gt[4*g+1], bx2=gt[4*g+2], by2=gt[4*g+3];
    float areaB = __fmul_rn(bx2-bx1+1.0f, by2-by1+1.0f);
    // overlap-possible position window (+1px float slop)
    int pxl = max(0,   (int)ceilf ((bx1 - 377.0f) * 0.0625f));
    int pxh = min(127, (int)floorf((bx2 + 362.0f) * 0.0625f));
    int pyl = max(0,   (int)ceilf ((by1 - 361.0f) * 0.0625f));
    int pyh = min(127, (int)floorf((by2 + 346.0f) * 0.0625f));
    uint32_t Wp = (uint32_t)(pxh - pxl + 1);
    int tot = (int)Wp * (pyh - pyl + 1);
    // magic division: m = ceil(2^22/Wp); exact for Wp<=128, pos<=16383
    uint32_t mdiv = (4194304u + Wp - 1u) / Wp;
    float a0[9],a1[9],a2[9],a3[9];
    #pragma unroll
    for (int t=0;t<9;++t){ a0[t]=c_base[t][0]; a1[t]=c_base[t][1];
                           a2[t]=c_base[t][2]; a3[t]=c_base[t][3]; }
    float best = -2.0f; int bi = 0;
    for (int pos = slice*256 + threadIdx.x; pos < tot; pos += 1024){
      uint32_t dq = (uint32_t)(((unsigned long long)(uint32_t)pos * mdiv) >> 22);
      int py = pyl + (int)dq;
      int px = pxl + (int)((uint32_t)pos - dq * Wp);
      int k = (py << 7) + px;           // ascending in pos -> first-occurrence ties
      float sx = 16.0f * (float)px;
      float sy = 16.0f * (float)py;
      #pragma unroll
      for (int t = 0; t < 9; ++t){
        float ax1=a0[t]+sx, ay1=a1[t]+sy, ax2=a2[t]+sx, ay2=a3[t]+sy;
        bool inside = (ax1 >= 0.0f) && (ay1 >= 0.0f) && (ax2 < W) && (ay2 < H);
        float iw = fminf(ax2,bx2) - fmaxf(ax1,bx1) + 1.0f;
        float ih = fminf(ay2,by2) - fmaxf(ay1,by1) + 1.0f;
        float ov = inside ? 0.0f : -1.0f;
        if (inside && iw > 0.0f && ih > 0.0f){
          float inter = __fmul_rn(iw, ih);
          ov = inter / ((c_areaA[t] + areaB) - inter);
        }
        if (ov > best){ best = ov; bi = k*9 + t; }
      }
    }
    unsigned long long p = 0ull;
    if (best >= 0.0f)
      p = ((unsigned long long)__float_as_uint(best) << 32) | (uint32_t)(~(uint32_t)bi);
    __shared__ unsigned long long sred[256];
    sred[threadIdx.x] = p;
    __syncthreads();
    for (int s = 128; s > 0; s >>= 1){
      if ((int)threadIdx.x < s){
        unsigned long long q = sred[threadIdx.x + s];
        if (q > sred[threadIdx.x]) sred[threadIdx.x] = q;
      }
      __syncthreads();
    }
    if (threadIdx.x == 0)
      reinterpret_cast<unsigned long long*>(ctl + W_GMAX2)[b2] = sred[0];
  }
}

// kC: each block redundantly derives the selection state (winners, counts, Tf)
// from kA's outputs (L2-hot ~7KB). 3 barriers: per-wave shfl count-reduction,
// dedup phase, final phase. Selection state computed redundantly per-thread
// in registers (uniform). Block 0 persists W_SEL for kD.
__global__ __launch_bounds__(256) void kC(const signed char* __restrict__ lab,
                                          const uint32_t* __restrict__ keys,
                                          float* __restrict__ out,
                                          uint32_t* __restrict__ ctl,
                                          uint32_t pk0, uint32_t pk1){
  int tid = threadIdx.x, bid = blockIdx.x;
  int wv = tid >> 6, lane = tid & 63;
  __shared__ uint32_t widx[NGT], wkey[NGT], wflag[256];
  __shared__ u64 wred[4];
  __shared__ int sdP, sdN;
  __shared__ uint32_t lcnt[2];

  int i = bid*256 + tid;
  int Lraw = lab[i];                 // early issue: latency hides under derivation
  uint32_t kraw = keys[i];           // garbage if Lraw<0 (never used then)

  wflag[tid] = 0xFFFFFFFFu;
  if (tid == 0){ sdP = 0; sdN = 0; lcnt[0] = 0u; lcnt[1] = 0u; }
  if (tid < NGT){
    const u64* g2 = reinterpret_cast<const u64*>(ctl + W_GMAX2);
    u64 best = 0ull;
    #pragma unroll
    for (int s = 0; s < 4; ++s){
      u64 q = g2[tid*4 + s];
      if (q > best) best = q;
    }
    uint32_t idx = best ? ~(uint32_t)best : 0xFFFFFFFFu;
    widx[tid] = idx;
    wkey[tid] = (idx != 0xFFFFFFFFu) ? rand_m23(pk0, pk1, idx) : 0u;
  }
  // per-block counts (packed u64: no cross-carry, sums < 2^32); wave shfl-reduce
  u64 acc = 0ull;
  for (int b = tid; b < 576; b += 256)
    acc += ((u64)ctl[W_CNTS + 2*b] << 32) | ctl[W_CNTS + 2*b + 1];
  #pragma unroll
  for (int off = 32; off > 0; off >>= 1)
    acc += __shfl_down(acc, off, 64);
  if (lane == 0) wred[wv] = acc;
  __syncthreads();                                   // B1
  if (tid < NGT && widx[tid] != 0xFFFFFFFFu){
    uint32_t idx = widx[tid];
    if ((idx >> 8) == (uint32_t)bid) wflag[idx & 255u] = wkey[tid];
    bool resp = true;                     // dedup: first gt owns a shared winner
    for (int g = 0; g < tid; ++g) if (widx[g] == idx){ resp = false; break; }
    if (resp){
      int oldL = lab[idx];
      if (oldL != 1){ atomicAdd(&sdP, 1); if (oldL == 0) atomicAdd(&sdN, 1); }
    }
  }
  __syncthreads();                                   // B2
  u64 tot = wred[0] + wred[1] + wred[2] + wred[3];
  uint32_t cntP = (uint32_t)(tot >> 32) + (uint32_t)sdP;
  uint32_t cntN = (uint32_t)tot - (uint32_t)sdN;
  uint32_t keepP = cntP < 128u ? cntP : 128u;
  uint32_t keepN = cntN < (256u - keepP) ? cntN : (256u - keepP);
  uint32_t Tf[2], kp[2], al[2];
  {
    uint32_t cnts[2] = {cntP, cntN}, keeps[2] = {keepP, keepN};
    #pragma unroll
    for (int c = 0; c < 2; ++c){
      uint32_t cnt = cnts[c], keep = keeps[c];
      al[c] = (keep >= cnt) ? 1u : 0u; kp[c] = keep; Tf[c] = 0u;
      if (!al[c]){
        u64 slack = 2ull * keep;          // mean survivors ~2*keep (>=8 sigma:
        if (slack < cnt)                  // keep>=128 in any non-keepAll ch)
          Tf[c] = (uint32_t)((((u64)(cnt - slack)) << 23) / cnt);
      }
    }
  }
  if (bid == 0 && tid == 0){
    #pragma unroll
    for (int c = 0; c < 2; ++c){
      ctl[W_SEL + c*4 + 0] = Tf[c];
      ctl[W_SEL + c*4 + 1] = kp[c];
      ctl[W_SEL + c*4 + 2] = al[c];
    }
  }
  int L = Lraw;
  uint32_t wf = wflag[tid];
  uint32_t m = (wf != 0xFFFFFFFFu) ? wf : kraw;
  if (wf != 0xFFFFFFFFu) L = 1;          // winner override (pos channel)
  if (L < 0){
    out[i] = -1.0f;
  } else {
    int ch = (L == 1) ? 0 : 1;
    if (al[ch]){
      out[i] = (float)L;
    } else if (m < Tf[ch]){
      out[i] = -1.0f;                    // provably below the cutoff
    } else {
      uint32_t pos = atomicAdd(&lcnt[ch], 1u);
      reinterpret_cast<u64*>(ctl + W_LIST)[(ch*576 + bid)*256 + pos] =
        ((u64)(m ^ 0x7FFFFFu) << 32) | (uint32_t)i;
    }
  }
  __syncthreads();                                   // B3
  if (tid < 2) ctl[W_LCNT + tid*576 + bid] = lcnt[tid];
}

// kD (1 block x 1024): gather survivors via parallel prefix scan (no
// same-address LDS atomics), rank-count (no sort), write labels.
// sk asc == (key desc, idx asc) == argsort rank order; all sk distinct.
__global__ __launch_bounds__(1024) void kD(float* __restrict__ out,
                                           uint32_t* __restrict__ ctl){
  int tid = threadIdx.x;
  __shared__ unsigned long long skey[MAXSURV];   // 16 KB
  __shared__ uint32_t scan[1024];                // 4 KB
  for (int c = 0; c < 2; ++c){
    uint32_t keep    = ctl[W_SEL + c*4 + 1];
    uint32_t keepAll = ctl[W_SEL + c*4 + 2];
    if (!keepAll){
      uint32_t cnum = (tid < 576) ? ctl[W_LCNT + c*576 + tid] : 0u;
      scan[tid] = cnum;
      __syncthreads();
      // Hillis-Steele inclusive scan over 1024 entries
      for (int off = 1; off < 1024; off <<= 1){
        uint32_t v = (tid >= off) ? scan[tid - off] : 0u;
        __syncthreads();
        scan[tid] += v;
        __syncthreads();
      }
      int n = (int)scan[1023]; if (n > MAXSURV) n = MAXSURV;
      if (cnum){
        uint32_t base = scan[tid] - cnum;   // exclusive prefix
        const unsigned long long* list =
          reinterpret_cast<const unsigned long long*>(ctl + W_LIST)
          + (size_t)(c*576 + tid)*256;
        for (uint32_t j = 0; j < cnum; ++j){
          uint32_t p = base + j;
          if (p < (uint32_t)MAXSURV) skey[p] = list[j];
        }
      }
      __syncthreads();
      float kv = (c == 0) ? 1.0f : 0.0f;
      for (int p = tid; p < n; p += 1024){
        unsigned long long mine = skey[p];
        uint32_t r = 0;
        for (int j = 0; j < n; ++j) r += (skey[j] < mine) ? 1u : 0u;  // LDS broadcast
        uint32_t idx = (uint32_t)(mine & 0xFFFFFFFFull);
        out[idx] = (r < keep) ? kv : -1.0f;
      }
    }
    __syncthreads();
  }
}

extern "C" void kernel_launch(void* const* d_in, const int* in_sizes, int n_in,
                              void* d_out, int out_size, void* d_ws, size_t ws_size,
                              hipStream_t stream) {
  const float* gt   = (const float*)d_in[1];   // (1,128,4)
  const float* meta = (const float*)d_in[2];   // (1,3) = {H, W, scale}
  float* out = (float*)d_out;                  // labels (147456) + targets (147456*4)
  signed char* lab = (signed char*)d_ws;
  uint32_t* keys = (uint32_t*)((char*)d_ws + N_ANCH);
  uint32_t* ctl  = keys + N_ANCH;

  // jax.random.key(42) = (0,42); partitionable split: key_i = enc(0, i) outputs
  uint32_t a0,a1,b0,b1;
  tf2x32(0u, 42u, 0u, 0u, &a0, &a1);   // k1 (positives)
  tf2x32(0u, 42u, 0u, 1u, &b0, &b1);   // k2 (negatives)

  kA<<<1088, 256, 0, stream>>>(gt, meta, lab, keys, ctl, out, a0, a1, b0, b1);
  kC<<<576, 256, 0, stream>>>(lab, keys, out, ctl, a0, a1);
  kD<<<1, 1024, 0, stream>>>(out, ctl);
}